// Round 2
// baseline (2232.458 us; speedup 1.0000x reference)
//
#include <hip/hip_runtime.h>
#include <math.h>

#define N_ATOMS 3072
#define C_Ac 128
#define C_Sc 384
#define C_Zc 16
#define QT 64          // queries per attention block
#define KC 16          // flash-decoding splits
#define CHUNK (N_ATOMS/KC)   // 192 keys per chunk
#define KT 8           // keys per sub-tile
#define NST (CHUNK/KT)       // 24 sub-tiles per block
#define NQT (N_ATOMS/QT)     // 48 q-tiles

__device__ __forceinline__ float sigm(float x){ return 1.f/(1.f+__expf(-x)); }

// ---------------- Stage A: AdaLN1 + QKV/G projections (8 rows/block) ----------------
// Column-parallel matmuls: thread owns 1-2 output cols, 8 rows -> 8-16 FMA per
// coalesced scalar weight load. Activations staged TRANSPOSED in LDS ([K][12] pad)
// and read as 2x float4 broadcast per K-step.
__global__ __launch_bounds__(256) void k_stage_a(
    const float* __restrict__ a, const float* __restrict__ s,
    const float* __restrict__ s_w, const float* __restrict__ scale_w,
    const float* __restrict__ scale_b, const float* __restrict__ shift_w,
    const float* __restrict__ wq, const float* __restrict__ bq,
    const float* __restrict__ wk, const float* __restrict__ wv,
    const float* __restrict__ wg,
    float* __restrict__ qo, float* __restrict__ ko, float* __restrict__ vo,
    float* __restrict__ go, float* __restrict__ lns)
{
  __shared__ __align__(16) float snT[C_Sc][12];    // 18 KB, transposed LN(s)*s_w
  __shared__ __align__(16) float an[8][C_Ac];      // 4 KB
  __shared__ __align__(16) float t1[8][C_Ac], t2[8][C_Ac];
  __shared__ __align__(16) float hshT[C_Ac][12];   // 6 KB, transposed h
  int n0 = blockIdx.x*8;
  int tid = threadIdx.x, w = tid>>6, lane = tid&63;

  // LN(s): wave handles rows w and w+4
  #pragma unroll
  for (int rr=0; rr<2; rr++){
    int r = w + rr*4;
    const float* srow = s + (size_t)(n0+r)*C_Sc;
    float v[6]; float sx=0.f, sxx=0.f;
    #pragma unroll
    for (int j=0;j<6;j++){ v[j]=srow[lane+j*64]; sx+=v[j]; sxx+=v[j]*v[j]; }
    #pragma unroll
    for (int off=32;off;off>>=1){ sx+=__shfl_xor(sx,off,64); sxx+=__shfl_xor(sxx,off,64); }
    float mean=sx*(1.f/C_Sc), rs=rsqrtf(sxx*(1.f/C_Sc)-mean*mean+1e-5f);
    #pragma unroll
    for (int j=0;j<6;j++){
      int i=lane+j*64;
      float ln=(v[j]-mean)*rs;
      lns[(size_t)(n0+r)*C_Sc+i]=ln;
      snT[i][r]=ln*s_w[i];
    }
  }
  // LN(a): wave handles rows w and w+4
  #pragma unroll
  for (int rr=0; rr<2; rr++){
    int r = w + rr*4;
    const float* arow = a + (size_t)(n0+r)*C_Ac;
    float v0=arow[lane], v1=arow[lane+64];
    float sx=v0+v1, sxx=v0*v0+v1*v1;
    #pragma unroll
    for (int off=32;off;off>>=1){ sx+=__shfl_xor(sx,off,64); sxx+=__shfl_xor(sxx,off,64); }
    float mean=sx*(1.f/C_Ac), rs=rsqrtf(sxx*(1.f/C_Ac)-mean*mean+1e-5f);
    an[r][lane]=(v0-mean)*rs; an[r][lane+64]=(v1-mean)*rs;
  }
  __syncthreads();

  { // AdaLN1 matmuls: sel0 -> sigmoid(scale), sel1 -> shift; 8 rows per thread
    int c = tid&127, sel = tid>>7;
    const float* W = sel ? shift_w : scale_w;
    float acc[8];
    float ini = sel ? 0.f : scale_b[c];
    #pragma unroll
    for (int r=0;r<8;r++) acc[r]=ini;
    #pragma unroll 4
    for (int i=0;i<C_Sc;i++){
      float wv = W[i*C_Ac+c];
      float4 s0 = *(const float4*)&snT[i][0];
      float4 s1 = *(const float4*)&snT[i][4];
      acc[0]=fmaf(s0.x,wv,acc[0]); acc[1]=fmaf(s0.y,wv,acc[1]);
      acc[2]=fmaf(s0.z,wv,acc[2]); acc[3]=fmaf(s0.w,wv,acc[3]);
      acc[4]=fmaf(s1.x,wv,acc[4]); acc[5]=fmaf(s1.y,wv,acc[5]);
      acc[6]=fmaf(s1.z,wv,acc[6]); acc[7]=fmaf(s1.w,wv,acc[7]);
    }
    if (sel==0){
      #pragma unroll
      for (int r=0;r<8;r++) t1[r][c]=sigm(acc[r]);
    } else {
      #pragma unroll
      for (int r=0;r<8;r++) t2[r][c]=acc[r];
    }
  }
  __syncthreads();
  for (int f=tid; f<8*C_Ac; f+=256){ int r=f>>7, c=f&127; hshT[c][r] = t1[r][c]*an[r][c] + t2[r][c]; }
  __syncthreads();

  { // QKVG: selA0 -> (q cols, v cols), selA1 -> (k cols, g cols)
    int c = tid&127, selA = tid>>7;
    const float* WA = selA ? wk : wq;
    const float* WB = selA ? wg : wv;
    float accA[8], accB[8];
    float ini = selA ? 0.f : bq[c];
    #pragma unroll
    for (int r=0;r<8;r++){ accA[r]=ini; accB[r]=0.f; }
    #pragma unroll 4
    for (int i=0;i<C_Ac;i++){
      float wa=WA[i*C_Ac+c], wb_=WB[i*C_Ac+c];
      float4 h0 = *(const float4*)&hshT[i][0];
      float4 h1 = *(const float4*)&hshT[i][4];
      accA[0]=fmaf(h0.x,wa,accA[0]); accA[1]=fmaf(h0.y,wa,accA[1]);
      accA[2]=fmaf(h0.z,wa,accA[2]); accA[3]=fmaf(h0.w,wa,accA[3]);
      accA[4]=fmaf(h1.x,wa,accA[4]); accA[5]=fmaf(h1.y,wa,accA[5]);
      accA[6]=fmaf(h1.z,wa,accA[6]); accA[7]=fmaf(h1.w,wa,accA[7]);
      accB[0]=fmaf(h0.x,wb_,accB[0]); accB[1]=fmaf(h0.y,wb_,accB[1]);
      accB[2]=fmaf(h0.z,wb_,accB[2]); accB[3]=fmaf(h0.w,wb_,accB[3]);
      accB[4]=fmaf(h1.x,wb_,accB[4]); accB[5]=fmaf(h1.y,wb_,accB[5]);
      accB[6]=fmaf(h1.z,wb_,accB[6]); accB[7]=fmaf(h1.w,wb_,accB[7]);
    }
    #pragma unroll
    for (int r=0;r<8;r++){
      size_t idx = (size_t)(n0+r)*C_Ac + c;
      if (selA==0){ qo[idx]=accA[r]; vo[idx]=accB[r]; }
      else        { ko[idx]=accA[r]; go[idx]=sigm(accB[r]); }
    }
  }
}

// ---------------- Stage B: flash-decoding attention with fused z bias ----------------
// 2-deep A/B register prefetch for z and K/V: the consumption wait becomes
// vmcnt(10) (newer buffer stays in flight) -> HBM continuously busy, no convoy.
__global__ __launch_bounds__(256) void k_attn(
    const float* __restrict__ z, const float* __restrict__ ln_z_w,
    const float* __restrict__ ln_z_b, const float* __restrict__ wb,
    const float* __restrict__ qws, const float* __restrict__ kws,
    const float* __restrict__ vws,
    float* __restrict__ part_m, float* __restrict__ part_l,
    float* __restrict__ part_o)
{
  __shared__ __align__(16) float bias[4][QT][KT+1];
  __shared__ __align__(16) float ks[KT][C_Ac];
  __shared__ __align__(16) float vs[KT][C_Ac];
  __shared__ float lwb_s[C_Zc][4];
  __shared__ float csum_s[4], bb_s[4];

  int qt = blockIdx.x, chunk = blockIdx.y;
  int q0 = qt*QT, k_base = chunk*CHUNK;
  int tid = threadIdx.x, w = tid>>6, lane = tid&63;

  if (tid < 64){ int c = tid>>2, h = tid&3; lwb_s[c][h] = ln_z_w[c]*wb[c*4+h]; }
  if (tid < 4){
    float cs=0.f, bbv=0.f;
    #pragma unroll
    for (int c=0;c<C_Zc;c++){ cs += ln_z_w[c]*wb[c*4+tid]; bbv += ln_z_b[c]*wb[c*4+tid]; }
    csum_s[tid]=cs; bb_s[tid]=bbv;
  }
  __syncthreads();   // before prefetch issue (so its implicit drain is harmless)

  float qv[32];
  {
    const float4* qp = (const float4*)(qws + (size_t)(q0+lane)*C_Ac + w*32);
    #pragma unroll
    for (int j=0;j<8;j++){ float4 t=qp[j]; qv[4*j]=t.x; qv[4*j+1]=t.y; qv[4*j+2]=t.z; qv[4*j+3]=t.w; }
  }
  float m=-INFINITY, l=0.f, o[32];
  #pragma unroll
  for (int j=0;j<32;j++) o[j]=0.f;
  const float isd = 0.17677669529663687f;

  const int qla = (tid>>3), qlb = 32 + (tid>>3), klz = tid&7;

  float z0A[16], z1A[16], z0B[16], z1B[16];
  float4 kregA, vregA, kregB, vregB;

#define LOADBUF(Z0, Z1, KR, VR, K0N)                                          \
  { int k0n = (K0N);                                                          \
    const float4* zp0 = (const float4*)(z + ((size_t)(q0+qla)*N_ATOMS + (k0n+klz))*C_Zc); \
    const float4* zp1 = (const float4*)(z + ((size_t)(q0+qlb)*N_ATOMS + (k0n+klz))*C_Zc); \
    _Pragma("unroll") for (int j=0;j<4;j++){ float4 t=zp0[j]; Z0[4*j]=t.x; Z0[4*j+1]=t.y; Z0[4*j+2]=t.z; Z0[4*j+3]=t.w; } \
    _Pragma("unroll") for (int j=0;j<4;j++){ float4 t=zp1[j]; Z1[4*j]=t.x; Z1[4*j+1]=t.y; Z1[4*j+2]=t.z; Z1[4*j+3]=t.w; } \
    KR = ((const float4*)(kws + (size_t)(k0n + (tid>>5))*C_Ac))[tid&31];      \
    VR = ((const float4*)(vws + (size_t)(k0n + (tid>>5))*C_Ac))[tid&31]; }

#define BIAS_PAIR(ZZ, QL)                                                     \
  { float sum=0.f, ssq=0.f;                                                   \
    _Pragma("unroll") for (int c=0;c<16;c++){ sum+=ZZ[c]; ssq+=ZZ[c]*ZZ[c]; } \
    float mz=sum*(1.f/16), rz=rsqrtf(ssq*(1.f/16)-mz*mz+1e-5f);               \
    float d0=0.f,d1=0.f,d2=0.f,d3=0.f;                                        \
    _Pragma("unroll") for (int c=0;c<16;c++){ float zc=ZZ[c];                 \
      d0=fmaf(zc,lwb_s[c][0],d0); d1=fmaf(zc,lwb_s[c][1],d1);                 \
      d2=fmaf(zc,lwb_s[c][2],d2); d3=fmaf(zc,lwb_s[c][3],d3); }               \
    bias[0][QL][klz]=rz*(d0-mz*csum_s[0])+bb_s[0];                            \
    bias[1][QL][klz]=rz*(d1-mz*csum_s[1])+bb_s[1];                            \
    bias[2][QL][klz]=rz*(d2-mz*csum_s[2])+bb_s[2];                            \
    bias[3][QL][klz]=rz*(d3-mz*csum_s[3])+bb_s[3]; }

#define MAIN_TILE()                                                           \
  { float lg[KT];                                                             \
    _Pragma("unroll") for (int kl=0;kl<KT;kl++) lg[kl] = bias[w][lane][kl];   \
    _Pragma("unroll") for (int kl=0;kl<KT;kl++){                              \
      const float4* kp = (const float4*)&ks[kl][w*32];                        \
      float d0=0.f,d1=0.f,d2=0.f,d3=0.f;                                      \
      _Pragma("unroll") for (int j=0;j<8;j++){ float4 t=kp[j];                \
        d0=fmaf(qv[4*j],t.x,d0); d1=fmaf(qv[4*j+1],t.y,d1);                   \
        d2=fmaf(qv[4*j+2],t.z,d2); d3=fmaf(qv[4*j+3],t.w,d3); }               \
      lg[kl] = fmaf((d0+d1)+(d2+d3), isd, lg[kl]);                            \
    }                                                                         \
    float tm = fmaxf(fmaxf(fmaxf(lg[0],lg[1]),fmaxf(lg[2],lg[3])),            \
                     fmaxf(fmaxf(lg[4],lg[5]),fmaxf(lg[6],lg[7])));           \
    float mn = fmaxf(m, tm);                                                  \
    float ef = __expf(m-mn);                                                  \
    float ssum = 0.f;                                                         \
    _Pragma("unroll") for (int kl=0;kl<KT;kl++){ float e=__expf(lg[kl]-mn); lg[kl]=e; ssum+=e; } \
    l = l*ef + ssum; m = mn;                                                  \
    _Pragma("unroll") for (int j=0;j<32;j++) o[j]*=ef;                        \
    _Pragma("unroll") for (int kl=0;kl<KT;kl++){                              \
      const float4* vp = (const float4*)&vs[kl][w*32];                        \
      float e = lg[kl];                                                       \
      _Pragma("unroll") for (int j=0;j<8;j++){ float4 t=vp[j];                \
        o[4*j]  =fmaf(e,t.x,o[4*j]);   o[4*j+1]=fmaf(e,t.y,o[4*j+1]);         \
        o[4*j+2]=fmaf(e,t.z,o[4*j+2]); o[4*j+3]=fmaf(e,t.w,o[4*j+3]); } } }

#define ROUND(Z0, Z1, KR, VR, ST)                                             \
  { ((float4*)ks)[tid] = KR;                                                  \
    ((float4*)vs)[tid] = VR;                                                  \
    BIAS_PAIR(Z0, qla);                                                       \
    BIAS_PAIR(Z1, qlb);                                                       \
    if ((ST)+2 < NST){ LOADBUF(Z0, Z1, KR, VR, k_base + ((ST)+2)*KT); }       \
    asm volatile("s_waitcnt lgkmcnt(0)" ::: "memory");                        \
    __builtin_amdgcn_s_barrier();                                             \
    MAIN_TILE();                                                              \
    asm volatile("s_waitcnt lgkmcnt(0)" ::: "memory");                        \
    __builtin_amdgcn_s_barrier(); }

  // prologue: sub-tiles 0 (A) and 1 (B)
  LOADBUF(z0A, z1A, kregA, vregA, k_base);
  LOADBUF(z0B, z1B, kregB, vregB, k_base + KT);

  #pragma unroll 1
  for (int st=0; st<NST; st+=2){
    ROUND(z0A, z1A, kregA, vregA, st);
    ROUND(z0B, z1B, kregB, vregB, st+1);
  }

  // write partials
  size_t pb = (((size_t)chunk*NQT + qt)*4 + w)*64 + lane;
  part_m[pb]=m; part_l[pb]=l;
  float4* po = (float4*)(part_o + pb*32);
  #pragma unroll
  for (int j=0;j<8;j++){ po[j] = make_float4(o[4*j],o[4*j+1],o[4*j+2],o[4*j+3]); }
#undef ROUND
#undef MAIN_TILE
#undef BIAS_PAIR
#undef LOADBUF
}

// ---------------- Stage B2: combine partials + gate ----------------
__global__ __launch_bounds__(256) void k_combine(
    const float* __restrict__ part_m, const float* __restrict__ part_l,
    const float* __restrict__ part_o, const float* __restrict__ gws,
    float* __restrict__ gows)
{
  int qt = blockIdx.x, h = blockIdx.y;
  int tid = threadIdx.x, ql = tid&63, dg = tid>>6;
  float mc[KC], lc[KC], M=-INFINITY;
  #pragma unroll
  for (int c=0;c<KC;c++){
    size_t pb = (((size_t)c*NQT + qt)*4 + h)*64 + ql;
    mc[c]=part_m[pb]; lc[c]=part_l[pb]; M=fmaxf(M,mc[c]);
  }
  float L=0.f, oa[8];
  #pragma unroll
  for (int j=0;j<8;j++) oa[j]=0.f;
  #pragma unroll
  for (int c=0;c<KC;c++){
    float sc=__expf(mc[c]-M);
    L += lc[c]*sc;
    const float4* po = (const float4*)(part_o + ((((size_t)c*NQT + qt)*4 + h)*64 + ql)*32 + dg*8);
    float4 t0=po[0], t1=po[1];
    oa[0]+=sc*t0.x; oa[1]+=sc*t0.y; oa[2]+=sc*t0.z; oa[3]+=sc*t0.w;
    oa[4]+=sc*t1.x; oa[5]+=sc*t1.y; oa[6]+=sc*t1.z; oa[7]+=sc*t1.w;
  }
  float invL = 1.f/L;
  size_t base = (size_t)(qt*64+ql)*C_Ac + h*32 + dg*8;
  #pragma unroll
  for (int j=0;j<8;j++) gows[base+j] = gws[base+j]*oa[j]*invL;
}

// ---------------- Stage C: out-proj + gates + transition (8 rows/block) ----------------
__global__ __launch_bounds__(256) void k_stage_c(
    const float* __restrict__ gows, const float* __restrict__ wo,
    const float* __restrict__ s, const float* __restrict__ sgate1_w,
    const float* __restrict__ sgate1_b, const float* __restrict__ a,
    const float* __restrict__ lns, const float* __restrict__ s_w2,
    const float* __restrict__ scale_w2, const float* __restrict__ scale_b2,
    const float* __restrict__ shift_w2, const float* __restrict__ w1,
    const float* __restrict__ w2, const float* __restrict__ wout,
    const float* __restrict__ sgate2_w, const float* __restrict__ sgate2_b,
    float* __restrict__ out)
{
  // 64 KB pooled LDS with explicit aliasing
  __shared__ __align__(16) float POOL[16384];
#define sT(i,r)     POOL[(i)*12+(r)]                 // [384][12] raw s, transposed
#define sn2T(i,r)   POOL[4608+(i)*12+(r)]            // [384][12] lns*s_w2, transposed
#define gatedT(i,r) POOL[4608+(i)*12+(r)]            // [256][12] aliases sn2T (dead after P3)
#define gorT(i,r)   POOL[9216+(i)*12+(r)]            // [128][12] gated attn out, transposed
#define tbM(r,c)    POOL[9216+(r)*C_Ac+(c)]          // [8][128] aliases gorT (dead after P1)
#define atsM(r,c)   POOL[10752+(r)*C_Ac+(c)]         // [8][128] residual-1
#define anvM(r,c)   POOL[11776+(r)*C_Ac+(c)]         // [8][128] LN(ats)
#define t1M(r,c)    POOL[12800+(r)*C_Ac+(c)]         // [8][128] outproj -> later ff
#define t2M(r,c)    POOL[13824+(r)*C_Ac+(c)]         // [8][128] gate1 -> ta -> gate2
#define h2T(i,r)    POOL[14848+(i)*12+(r)]           // [128][12] h2, transposed
  int n0 = blockIdx.x*8;
  int tid = threadIdx.x, w = tid>>6, lane = tid&63;

  // stage sT, sn2T (transposed), gorT
  for (int r=0;r<8;r++)
    for (int i=tid;i<C_Sc;i+=256){
      sT(i,r)   = s[(size_t)(n0+r)*C_Sc+i];
      sn2T(i,r) = lns[(size_t)(n0+r)*C_Sc+i]*s_w2[i];
    }
  for (int f=tid; f<8*C_Ac; f+=256){ int r=f>>7, c=f&127; gorT(c,r)=gows[(size_t)(n0+r)*C_Ac+c]; }
  __syncthreads();

  { // P1: sel0 -> out-proj (K=128); sel1 -> sigmoid(s-gate1) (K=384)
    int c = tid&127, sel = tid>>7;
    float acc[8];
    if (sel==0){
      #pragma unroll
      for (int r=0;r<8;r++) acc[r]=0.f;
      #pragma unroll 4
      for (int i=0;i<C_Ac;i++){
        float wv=wo[i*C_Ac+c];
        float4 g0=*(const float4*)&gorT(i,0), g1=*(const float4*)&gorT(i,4);
        acc[0]=fmaf(g0.x,wv,acc[0]); acc[1]=fmaf(g0.y,wv,acc[1]);
        acc[2]=fmaf(g0.z,wv,acc[2]); acc[3]=fmaf(g0.w,wv,acc[3]);
        acc[4]=fmaf(g1.x,wv,acc[4]); acc[5]=fmaf(g1.y,wv,acc[5]);
        acc[6]=fmaf(g1.z,wv,acc[6]); acc[7]=fmaf(g1.w,wv,acc[7]);
      }
      #pragma unroll
      for (int r=0;r<8;r++) t1M(r,c)=acc[r];
    } else {
      #pragma unroll
      for (int r=0;r<8;r++) acc[r]=sgate1_b[c];
      #pragma unroll 4
      for (int i=0;i<C_Sc;i++){
        float wv=sgate1_w[i*C_Ac+c];
        float4 s0=*(const float4*)&sT(i,0), s1=*(const float4*)&sT(i,4);
        acc[0]=fmaf(s0.x,wv,acc[0]); acc[1]=fmaf(s0.y,wv,acc[1]);
        acc[2]=fmaf(s0.z,wv,acc[2]); acc[3]=fmaf(s0.w,wv,acc[3]);
        acc[4]=fmaf(s1.x,wv,acc[4]); acc[5]=fmaf(s1.y,wv,acc[5]);
        acc[6]=fmaf(s1.z,wv,acc[6]); acc[7]=fmaf(s1.w,wv,acc[7]);
      }
      #pragma unroll
      for (int r=0;r<8;r++) t2M(r,c)=sigm(acc[r]);
    }
  }
  __syncthreads();
  for (int f=tid; f<8*C_Ac; f+=256){ int r=f>>7, c=f&127;
    atsM(r,c) = t2M(r,c)*t1M(r,c) + a[(size_t)(n0+r)*C_Ac+c]; }
  __syncthreads();

  // LN(ats): wave handles rows w, w+4
  #pragma unroll
  for (int rr=0; rr<2; rr++){
    int r = w + rr*4;
    float v0=atsM(r,lane), v1=atsM(r,lane+64);
    float sx=v0+v1, sxx=v0*v0+v1*v1;
    #pragma unroll
    for (int off=32;off;off>>=1){ sx+=__shfl_xor(sx,off,64); sxx+=__shfl_xor(sxx,off,64); }
    float mean=sx*(1.f/C_Ac), rs=rsqrtf(sxx*(1.f/C_Ac)-mean*mean+1e-5f);
    anvM(r,lane)=(v0-mean)*rs; anvM(r,lane+64)=(v1-mean)*rs;
  }
  __syncthreads();

  { // P3: AdaLN2: sel0 -> ta = sigm(scale2)*anv (into t2M); sel1 -> tb = shift2
    int c = tid&127, sel = tid>>7;
    const float* W = sel ? shift_w2 : scale_w2;
    float acc[8];
    float ini = sel ? 0.f : scale_b2[c];
    #pragma unroll
    for (int r=0;r<8;r++) acc[r]=ini;
    #pragma unroll 4
    for (int i=0;i<C_Sc;i++){
      float wv=W[i*C_Ac+c];
      float4 s0=*(const float4*)&sn2T(i,0), s1=*(const float4*)&sn2T(i,4);
      acc[0]=fmaf(s0.x,wv,acc[0]); acc[1]=fmaf(s0.y,wv,acc[1]);
      acc[2]=fmaf(s0.z,wv,acc[2]); acc[3]=fmaf(s0.w,wv,acc[3]);
      acc[4]=fmaf(s1.x,wv,acc[4]); acc[5]=fmaf(s1.y,wv,acc[5]);
      acc[6]=fmaf(s1.z,wv,acc[6]); acc[7]=fmaf(s1.w,wv,acc[7]);
    }
    if (sel==0){
      #pragma unroll
      for (int r=0;r<8;r++) t2M(r,c)=sigm(acc[r])*anvM(r,c);
    } else {
      #pragma unroll
      for (int r=0;r<8;r++) tbM(r,c)=acc[r];
    }
  }
  __syncthreads();
  for (int f=tid; f<8*C_Ac; f+=256){ int r=f>>7, c=f&127; h2T(c,r)=t2M(r,c)+tbM(r,c); }
  __syncthreads();

  { // P4: SwiGLU hidden: thread owns col tid of 256 for both w1 and w2
    float a1[8], a2[8];
    #pragma unroll
    for (int r=0;r<8;r++){ a1[r]=0.f; a2[r]=0.f; }
    #pragma unroll 2
    for (int i=0;i<C_Ac;i++){
      float w1v=w1[i*2*C_Ac+tid], w2v=w2[i*2*C_Ac+tid];
      float4 h0=*(const float4*)&h2T(i,0), h1=*(const float4*)&h2T(i,4);
      a1[0]=fmaf(h0.x,w1v,a1[0]); a1[1]=fmaf(h0.y,w1v,a1[1]);
      a1[2]=fmaf(h0.z,w1v,a1[2]); a1[3]=fmaf(h0.w,w1v,a1[3]);
      a1[4]=fmaf(h1.x,w1v,a1[4]); a1[5]=fmaf(h1.y,w1v,a1[5]);
      a1[6]=fmaf(h1.z,w1v,a1[6]); a1[7]=fmaf(h1.w,w1v,a1[7]);
      a2[0]=fmaf(h0.x,w2v,a2[0]); a2[1]=fmaf(h0.y,w2v,a2[1]);
      a2[2]=fmaf(h0.z,w2v,a2[2]); a2[3]=fmaf(h0.w,w2v,a2[3]);
      a2[4]=fmaf(h1.x,w2v,a2[4]); a2[5]=fmaf(h1.y,w2v,a2[5]);
      a2[6]=fmaf(h1.z,w2v,a2[6]); a2[7]=fmaf(h1.w,w2v,a2[7]);
    }
    #pragma unroll
    for (int r=0;r<8;r++) gatedT(tid,r)=a1[r]*sigm(a1[r])*a2[r];
  }
  __syncthreads();

  { // P5: sel0 -> ff = gated@wout (K=256, into t1M); sel1 -> sigmoid(s-gate2) (into t2M)
    int c = tid&127, sel = tid>>7;
    float acc[8];
    if (sel==0){
      #pragma unroll
      for (int r=0;r<8;r++) acc[r]=0.f;
      #pragma unroll 4
      for (int i=0;i<2*C_Ac;i++){
        float wv=wout[i*C_Ac+c];
        float4 g0=*(const float4*)&gatedT(i,0), g1=*(const float4*)&gatedT(i,4);
        acc[0]=fmaf(g0.x,wv,acc[0]); acc[1]=fmaf(g0.y,wv,acc[1]);
        acc[2]=fmaf(g0.z,wv,acc[2]); acc[3]=fmaf(g0.w,wv,acc[3]);
        acc[4]=fmaf(g1.x,wv,acc[4]); acc[5]=fmaf(g1.y,wv,acc[5]);
        acc[6]=fmaf(g1.z,wv,acc[6]); acc[7]=fmaf(g1.w,wv,acc[7]);
      }
      #pragma unroll
      for (int r=0;r<8;r++) t1M(r,c)=acc[r];
    } else {
      #pragma unroll
      for (int r=0;r<8;r++) acc[r]=sgate2_b[c];
      #pragma unroll 4
      for (int i=0;i<C_Sc;i++){
        float wv=sgate2_w[i*C_Ac+c];
        float4 s0=*(const float4*)&sT(i,0), s1=*(const float4*)&sT(i,4);
        acc[0]=fmaf(s0.x,wv,acc[0]); acc[1]=fmaf(s0.y,wv,acc[1]);
        acc[2]=fmaf(s0.z,wv,acc[2]); acc[3]=fmaf(s0.w,wv,acc[3]);
        acc[4]=fmaf(s1.x,wv,acc[4]); acc[5]=fmaf(s1.y,wv,acc[5]);
        acc[6]=fmaf(s1.z,wv,acc[6]); acc[7]=fmaf(s1.w,wv,acc[7]);
      }
      #pragma unroll
      for (int r=0;r<8;r++) t2M(r,c)=sigm(acc[r]);
    }
  }
  __syncthreads();
  for (int f=tid; f<8*C_Ac; f+=256){ int r=f>>7, c=f&127;
    out[(size_t)(n0+r)*C_Ac+c] = t2M(r,c)*t1M(r,c) + atsM(r,c); }
#undef sT
#undef sn2T
#undef gatedT
#undef gorT
#undef tbM
#undef atsM
#undef anvM
#undef t1M
#undef t2M
#undef h2T
}

extern "C" void kernel_launch(void* const* d_in, const int* in_sizes, int n_in,
                              void* d_out, int out_size, void* d_ws, size_t ws_size,
                              hipStream_t stream)
{
  const float* a            = (const float*)d_in[0];
  const float* s            = (const float*)d_in[1];
  const float* z            = (const float*)d_in[2];
  const float* aln1_s_w     = (const float*)d_in[3];
  const float* aln1_scale_w = (const float*)d_in[4];
  const float* aln1_scale_b = (const float*)d_in[5];
  const float* aln1_shift_w = (const float*)d_in[6];
  const float* wq           = (const float*)d_in[7];
  const float* bq           = (const float*)d_in[8];
  const float* wk           = (const float*)d_in[9];
  const float* wv           = (const float*)d_in[10];
  const float* ln_z_w       = (const float*)d_in[11];
  const float* ln_z_b       = (const float*)d_in[12];
  const float* wb           = (const float*)d_in[13];
  const float* wg           = (const float*)d_in[14];
  const float* wo           = (const float*)d_in[15];
  const float* sgate1_w     = (const float*)d_in[16];
  const float* sgate1_b     = (const float*)d_in[17];
  const float* aln2_s_w     = (const float*)d_in[18];
  const float* aln2_scale_w = (const float*)d_in[19];
  const float* aln2_scale_b = (const float*)d_in[20];
  const float* aln2_shift_w = (const float*)d_in[21];
  const float* w1           = (const float*)d_in[22];
  const float* w2           = (const float*)d_in[23];
  const float* wout         = (const float*)d_in[24];
  const float* sgate2_w     = (const float*)d_in[25];
  const float* sgate2_b     = (const float*)d_in[26];
  float* out = (float*)d_out;

  float* ws   = (float*)d_ws;
  float* qws  = ws;                               // N*C_A
  float* kws  = qws  + (size_t)N_ATOMS*C_Ac;
  float* vws  = kws  + (size_t)N_ATOMS*C_Ac;
  float* gws  = vws  + (size_t)N_ATOMS*C_Ac;
  float* gows = gws  + (size_t)N_ATOMS*C_Ac;
  float* lns  = gows + (size_t)N_ATOMS*C_Ac;      // N*C_S
  float* part_m = lns + (size_t)N_ATOMS*C_Sc;     // KC*NQT*4*64
  float* part_l = part_m + (size_t)KC*NQT*4*64;
  float* part_o = part_l + (size_t)KC*NQT*4*64;   // KC*NQT*4*64*32

  hipLaunchKernelGGL(k_stage_a, dim3(N_ATOMS/8), dim3(256), 0, stream,
      a, s, aln1_s_w, aln1_scale_w, aln1_scale_b, aln1_shift_w,
      wq, bq, wk, wv, wg, qws, kws, vws, gws, lns);
  hipLaunchKernelGGL(k_attn, dim3(NQT, KC), dim3(256), 0, stream,
      z, ln_z_w, ln_z_b, wb, qws, kws, vws, part_m, part_l, part_o);
  hipLaunchKernelGGL(k_combine, dim3(NQT, 4), dim3(256), 0, stream,
      part_m, part_l, part_o, gws, gows);
  hipLaunchKernelGGL(k_stage_c, dim3(N_ATOMS/8), dim3(256), 0, stream,
      gows, wo, s, sgate1_w, sgate1_b, a, lns, aln2_s_w,
      aln2_scale_w, aln2_scale_b, aln2_shift_w, w1, w2, wout,
      sgate2_w, sgate2_b, out);
}